// Round 8
// baseline (193.436 us; speedup 1.0000x reference)
//
#include <hip/hip_runtime.h>

#define HID 256
#define K27 27

typedef __attribute__((ext_vector_type(8))) short    bf16x8;
typedef __attribute__((ext_vector_type(4))) float    f32x4;
typedef __attribute__((ext_vector_type(4))) unsigned u32x4;

static __device__ __forceinline__ unsigned short f2bf(float f) {
    union { float f; unsigned u; } v; v.f = f;   // cold path only (staging)
    return (unsigned short)((v.u + 0x7FFFu + ((v.u >> 16) & 1u)) >> 16);
}
// (lo,hi) -> one u32 holding 2 bf16, single v_cvt_pk_bf16_f32
static __device__ __forceinline__ unsigned pack2bf(float lo, float hi) {
    unsigned r;
    asm("v_cvt_pk_bf16_f32 %0, %1, %2" : "=v"(r) : "v"(lo), "v"(hi));
    return r;
}
static __device__ __forceinline__ bf16x8 as_bf16x8(u32x4 u) {
    return __builtin_bit_cast(bf16x8, u);
}
// fragment with only element 0 (low bf16 of word 0) populated
static __device__ __forceinline__ bf16x8 frag1(unsigned u) {
    u32x4 t = {u, 0u, 0u, 0u};
    return __builtin_bit_cast(bf16x8, t);
}
static __device__ __forceinline__ float lk(float x) {   // leaky_relu(0.01)
    return fmaxf(x, 0.01f * x);
}
// s += dpp_perm(s): VALU-only cross-lane add (no LDS pipe, low latency)
#define DPP_ADD(s, ctrl) \
    s += __builtin_bit_cast(float, __builtin_amdgcn_update_dpp( \
            0, __builtin_bit_cast(int, s), ctrl, 0xF, 0xF, true))

// v7 = v6 with three stall-killers:
//  (1) L1 A-frags (W1|b1) register-resident: w1r[16], no per-iter LDS reads
//  (2) 16-lane reduce via DPP adds (quad_perm 0xB1/0x4E + row_ror:4/8),
//      replacing 4-deep ds_swizzle chains
//  (3) mapping+pos prefetched one iteration ahead so gather issue never
//      waits on the mapping load at iter head
__global__ __launch_bounds__(256, 4) void mapnet_v7(
    const float* __restrict__ pos,      // (P,3)
    const int*   __restrict__ mapping,  // (P,2)
    const float* __restrict__ feats,    // (3,512,512)
    const float* __restrict__ W1,       // (256,3)
    const float* __restrict__ b1,       // (256)
    const float* __restrict__ W2,       // (27,256)
    const float* __restrict__ b2,       // (27)
    float* __restrict__ out)            // (P)
{
    __shared__ bf16x8 sB[16][64];       // [kc*2+nt][lane]: L2 B-frags (16 KB)

    const int tid = threadIdx.x;
    // ---- stage L2 B-fragments, j-map matching the L1 output layout:
    //      j = 32kc + 16(e>>2) + 4g + (e&3)
    for (int e = tid; e < 1024; e += 256) {
        const int kcnt = e >> 6, l = e & 63;
        const int kc = kcnt >> 1, nt = kcnt & 1;
        const int gg = l >> 4, cc = l & 15;
        const int n = nt * 16 + cc;
        const int jbase = kc * 32 + 4 * gg;
        u32x4 bb;
        #pragma unroll
        for (int i = 0; i < 4; ++i) {
            const int jlo = jbase + 16 * (i >> 1) + 2 * (i & 1);
            float f0 = 0.f, f1 = 0.f;
            if (n < K27) { f0 = W2[n * HID + jlo]; f1 = W2[n * HID + jlo + 1]; }
            bb[i] = (unsigned)f2bf(f0) | ((unsigned)f2bf(f1) << 16);
        }
        sB[kcnt][l] = as_bf16x8(bb);
    }
    __syncthreads();

    const int lane = tid & 63, wid = tid >> 6;
    const int g = lane >> 4, col = lane & 15;

    // ---- L1 A-fragments in registers: lane (g,col) of tile jt holds
    //      W1[16jt+col][g] (g=3 -> b1), packed as bf16 in elem 0
    unsigned w1r[16];
    #pragma unroll
    for (int jt = 0; jt < 16; ++jt) {
        const int j = jt * 16 + col;
        const float val = (g < 3) ? W1[3 * j + g] : b1[j];
        w1r[jt] = pack2bf(val, 0.0f);
    }

    const float b2A = b2[col];
    const float b2B = (col < K27 - 16) ? b2[16 + col] : 0.0f;
    const int kA = col;
    const int cA = kA/9, dyA = (kA%9)/3 - 1, dxA = (kA%9)%3 - 1;
    const int kB = min(16 + col, K27 - 1);          // clamped -> valid addr; accB==0 there
    const int cB = kB/9, dyB = (kB%9)/3 - 1, dxB = (kB%9)%3 - 1;

    const float* fbaseA = feats + cA * (512*512);
    const float* fbaseB = feats + cB * (512*512);
    const int2*  map2   = (const int2*)mapping;

    const int w = blockIdx.x * 4 + wid;             // 0..8191

    // ---- prefetch mapping+pos for iter 0
    int2  mpc[8];
    float pc[6];
    {
        const int tb0 = (w * 8) * 16, tb1 = tb0 + 16;
        #pragma unroll
        for (int tt = 0; tt < 2; ++tt)
            #pragma unroll
            for (int r = 0; r < 4; ++r)
                mpc[tt*4 + r] = map2[(tt ? tb1 : tb0) + g*4 + r];
        pc[0] = pos[3*(tb0+col)]; pc[1] = pos[3*(tb0+col)+1]; pc[2] = pos[3*(tb0+col)+2];
        pc[3] = pos[3*(tb1+col)]; pc[4] = pos[3*(tb1+col)+1]; pc[5] = pos[3*(tb1+col)+2];
    }

    for (int it = 0; it < 4; ++it) {
        const int tb0 = (w * 8 + it * 2) * 16, tb1 = tb0 + 16;

        // L1 B-fragment: elem0 = pos component g (g=3 -> 1.0 bias slot)
        const float v0 = (g == 0) ? pc[0] : (g == 1) ? pc[1] : (g == 2) ? pc[2] : 1.0f;
        const float v1 = (g == 0) ? pc[3] : (g == 1) ? pc[4] : (g == 2) ? pc[5] : 1.0f;
        const bf16x8 pB0 = frag1(pack2bf(v0, 0.0f));
        const bf16x8 pB1 = frag1(pack2bf(v1, 0.0f));

        // ---- gathers for CURRENT iter (mapping already resident in mpc)
        float fvA[2][4], fvB[2][4];
        #pragma unroll
        for (int tt = 0; tt < 2; ++tt) {
            #pragma unroll
            for (int r = 0; r < 4; ++r) {
                const int my = mpc[tt*4 + r].x, mx = mpc[tt*4 + r].y;
                int y  = my + dyA, x  = mx + dxA;
                int yc = min(max(y,0),511), xc = min(max(x,0),511);
                float f = fbaseA[yc*512 + xc];
                fvA[tt][r] = (((unsigned)y | (unsigned)x) < 512u) ? f : 0.f;
                int y2 = my + dyB, x2 = mx + dxB;
                int yc2 = min(max(y2,0),511), xc2 = min(max(x2,0),511);
                float f2 = fbaseB[yc2*512 + xc2];
                fvB[tt][r] = (((unsigned)y2 | (unsigned)x2) < 512u) ? f2 : 0.f;
            }
        }

        // ---- prefetch mapping+pos for NEXT iter (latency hides under kc loop)
        int2  mpn[8];
        float pn[6];
        if (it < 3) {
            const int nb0 = (w * 8 + (it+1) * 2) * 16, nb1 = nb0 + 16;
            #pragma unroll
            for (int tt = 0; tt < 2; ++tt)
                #pragma unroll
                for (int r = 0; r < 4; ++r)
                    mpn[tt*4 + r] = map2[(tt ? nb1 : nb0) + g*4 + r];
            pn[0] = pos[3*(nb0+col)]; pn[1] = pos[3*(nb0+col)+1]; pn[2] = pos[3*(nb0+col)+2];
            pn[3] = pos[3*(nb1+col)]; pn[4] = pos[3*(nb1+col)+1]; pn[5] = pos[3*(nb1+col)+2];
        } else {
            #pragma unroll
            for (int i = 0; i < 8; ++i) mpn[i] = mpc[i];
            #pragma unroll
            for (int i = 0; i < 6; ++i) pn[i] = pc[i];
        }

        f32x4 acc00 = {b2A,b2A,b2A,b2A}, acc01 = {b2B,b2B,b2B,b2B};
        f32x4 acc10 = {b2A,b2A,b2A,b2A}, acc11 = {b2B,b2B,b2B,b2B};
        const f32x4 zero = {0.f, 0.f, 0.f, 0.f};

        #pragma unroll
        for (int kc = 0; kc < 8; ++kc) {
            const bf16x8 wA0 = frag1(w1r[2*kc    ]);
            const bf16x8 wA1 = frag1(w1r[2*kc + 1]);

            // L1: h[j][px]; lane holds j = 16jt + 4g + reg, px = col
            const f32x4 c00 = __builtin_amdgcn_mfma_f32_16x16x32_bf16(wA0, pB0, zero, 0,0,0);
            const f32x4 c01 = __builtin_amdgcn_mfma_f32_16x16x32_bf16(wA1, pB0, zero, 0,0,0);
            const f32x4 c10 = __builtin_amdgcn_mfma_f32_16x16x32_bf16(wA0, pB1, zero, 0,0,0);
            const f32x4 c11 = __builtin_amdgcn_mfma_f32_16x16x32_bf16(wA1, pB1, zero, 0,0,0);

            // leaky + pack -> L2 A-fragment
            u32x4 a0, a1;
            a0[0] = pack2bf(lk(c00[0]), lk(c00[1]));
            a0[1] = pack2bf(lk(c00[2]), lk(c00[3]));
            a0[2] = pack2bf(lk(c01[0]), lk(c01[1]));
            a0[3] = pack2bf(lk(c01[2]), lk(c01[3]));
            a1[0] = pack2bf(lk(c10[0]), lk(c10[1]));
            a1[1] = pack2bf(lk(c10[2]), lk(c10[3]));
            a1[2] = pack2bf(lk(c11[0]), lk(c11[1]));
            a1[3] = pack2bf(lk(c11[2]), lk(c11[3]));
            const bf16x8 av0 = as_bf16x8(a0);
            const bf16x8 av1 = as_bf16x8(a1);

            const bf16x8 bv0 = sB[kc*2    ][lane];
            const bf16x8 bv1 = sB[kc*2 + 1][lane];
            acc00 = __builtin_amdgcn_mfma_f32_16x16x32_bf16(av0, bv0, acc00, 0,0,0);
            acc01 = __builtin_amdgcn_mfma_f32_16x16x32_bf16(av0, bv1, acc01, 0,0,0);
            acc10 = __builtin_amdgcn_mfma_f32_16x16x32_bf16(av1, bv0, acc10, 0,0,0);
            acc11 = __builtin_amdgcn_mfma_f32_16x16x32_bf16(av1, bv1, acc11, 0,0,0);
        }

        // ---- combine: C/D layout col=lane&15 (k27), row=g*4+r (pixel);
        //      16-lane sum via DPP (xor1, xor2 quad_perms, then ror4+ror8)
        #pragma unroll
        for (int tt = 0; tt < 2; ++tt) {
            const int tb = tt ? tb1 : tb0;
            const f32x4 aA = tt ? acc10 : acc00;
            const f32x4 aB = tt ? acc11 : acc01;
            #pragma unroll
            for (int r = 0; r < 4; ++r) {
                float s = aA[r] * fvA[tt][r] + aB[r] * fvB[tt][r];
                DPP_ADD(s, 0xB1);    // quad_perm(1,0,3,2)  : xor 1
                DPP_ADD(s, 0x4E);    // quad_perm(2,3,0,1)  : xor 2
                DPP_ADD(s, 0x124);   // row_ror:4
                DPP_ADD(s, 0x128);   // row_ror:8
                if (col == r) out[tb + g*4 + r] = s;
            }
        }

        // rotate prefetch buffers
        #pragma unroll
        for (int i = 0; i < 8; ++i) mpc[i] = mpn[i];
        #pragma unroll
        for (int i = 0; i < 6; ++i) pc[i] = pn[i];
    }
}

extern "C" void kernel_launch(void* const* d_in, const int* in_sizes, int n_in,
                              void* d_out, int out_size, void* d_ws, size_t ws_size,
                              hipStream_t stream) {
    const float* pos     = (const float*)d_in[0];
    const int*   mapping = (const int*)d_in[1];
    const float* feats   = (const float*)d_in[2];
    // d_in[3] = depth, unused
    const float* W1      = (const float*)d_in[4];
    const float* b1      = (const float*)d_in[5];
    const float* W2      = (const float*)d_in[6];
    const float* b2      = (const float*)d_in[7];
    float* out = (float*)d_out;

    // P = 1024*1024: 65536 tiles; 2048 blocks x 4 waves x 8 tiles
    mapnet_v7<<<2048, 256, 0, stream>>>(pos, mapping, feats, W1, b1, W2, b2, out);
}

// Round 11
// 77.970 us; speedup vs baseline: 2.4809x; 2.4809x over previous
//
#include <hip/hip_runtime.h>

#define HID 256
#define K27 27

typedef __attribute__((ext_vector_type(8))) short    bf16x8;
typedef __attribute__((ext_vector_type(4))) float    f32x4;
typedef __attribute__((ext_vector_type(4))) unsigned u32x4;

static __device__ __forceinline__ unsigned short f2bf(float f) {
    union { float f; unsigned u; } v; v.f = f;   // cold path only (staging)
    return (unsigned short)((v.u + 0x7FFFu + ((v.u >> 16) & 1u)) >> 16);
}
static __device__ __forceinline__ unsigned pack2bf(float lo, float hi) {
    unsigned r;
    asm("v_cvt_pk_bf16_f32 %0, %1, %2" : "=v"(r) : "v"(lo), "v"(hi));
    return r;
}
static __device__ __forceinline__ bf16x8 as_bf16x8(u32x4 u) {
    return __builtin_bit_cast(bf16x8, u);
}
static __device__ __forceinline__ bf16x8 frag1(unsigned u) {
    u32x4 t = {u, 0u, 0u, 0u};
    return __builtin_bit_cast(bf16x8, t);
}
static __device__ __forceinline__ float lk(float x) {   // leaky_relu(0.01)
    return fmaxf(x, 0.01f * x);
}
// s += dpp_perm(s): VALU-only cross-lane add (semantics verified by v7's pass)
#define DPP_ADD(s, ctrl) \
    s += __builtin_bit_cast(float, __builtin_amdgcn_update_dpp( \
            0, __builtin_bit_cast(int, s), ctrl, 0xF, 0xF, true))

// v10 = v6 (verified 80us kernel) with EXACTLY ONE change: the 16-lane
// combine reduction uses DPP (quad_perm xor1/xor2 + row_ror:4/8, pure VALU)
// instead of 4-deep __shfl_xor chains. No workspace, no pad, single kernel.
// Purpose: isolate the v8/v9 NaN (pad path vs DPP-in-this-structure).
__global__ __launch_bounds__(256, 4) void mapnet_v10(
    const float* __restrict__ pos,      // (P,3)
    const int*   __restrict__ mapping,  // (P,2)
    const float* __restrict__ feats,    // (3,512,512)
    const float* __restrict__ W1,       // (256,3)
    const float* __restrict__ b1,       // (256)
    const float* __restrict__ W2,       // (27,256)
    const float* __restrict__ b2,       // (27)
    float* __restrict__ out)            // (P)
{
    __shared__ unsigned sW1f[16][64];   // [jt][lane]: pack2bf(W1val,0)  (4 KB)
    __shared__ bf16x8   sB[16][64];     // [kc*2+nt][lane]: L2 B-frags   (16 KB)

    const int tid = threadIdx.x;

    // ---- stage L1 A-fragments: lane (g,cc) of tile jt holds W1[16jt+cc][g] (g=3 -> b1)
    for (int e = tid; e < 1024; e += 256) {
        const int jt = e >> 6, l = e & 63;
        const int gg = l >> 4, cc = l & 15;
        const int j = jt * 16 + cc;
        const float val = (gg < 3) ? W1[3 * j + gg] : b1[j];
        sW1f[jt][l] = pack2bf(val, 0.0f);
    }
    // ---- stage L2 B-fragments, j-map matching L1 output: j = 32kc+16(e>>2)+4g+(e&3)
    for (int e = tid; e < 1024; e += 256) {
        const int kcnt = e >> 6, l = e & 63;
        const int kc = kcnt >> 1, nt = kcnt & 1;
        const int gg = l >> 4, cc = l & 15;
        const int n = nt * 16 + cc;
        const int jbase = kc * 32 + 4 * gg;
        u32x4 bb;
        #pragma unroll
        for (int i = 0; i < 4; ++i) {
            const int jlo = jbase + 16 * (i >> 1) + 2 * (i & 1);
            float f0 = 0.f, f1 = 0.f;
            if (n < K27) { f0 = W2[n * HID + jlo]; f1 = W2[n * HID + jlo + 1]; }
            bb[i] = (unsigned)f2bf(f0) | ((unsigned)f2bf(f1) << 16);
        }
        sB[kcnt][l] = as_bf16x8(bb);
    }
    __syncthreads();

    const int lane = tid & 63, wid = tid >> 6;
    const int g = lane >> 4, col = lane & 15;

    const float b2A = b2[col];
    const float b2B = (col < K27 - 16) ? b2[16 + col] : 0.0f;
    const int kA = col;
    const int cA = kA/9, dyA = (kA%9)/3 - 1, dxA = (kA%9)%3 - 1;
    const int kB = min(16 + col, K27 - 1);          // clamped -> valid addr; accB==0 there
    const int cB = kB/9, dyB = (kB%9)/3 - 1, dxB = (kB%9)%3 - 1;

    const float* fbaseA = feats + cA * (512*512);
    const float* fbaseB = feats + cB * (512*512);
    const int2*  map2   = (const int2*)mapping;

    const int w = blockIdx.x * 4 + wid;             // 0..8191

    for (int it = 0; it < 4; ++it) {
        const int tb0 = (w * 8 + it * 2) * 16, tb1 = tb0 + 16;

        const float q00 = pos[3*(tb0+col)], q01 = pos[3*(tb0+col)+1], q02 = pos[3*(tb0+col)+2];
        const float q10 = pos[3*(tb1+col)], q11 = pos[3*(tb1+col)+1], q12 = pos[3*(tb1+col)+2];
        const float v0 = (g == 0) ? q00 : (g == 1) ? q01 : (g == 2) ? q02 : 1.0f;
        const float v1 = (g == 0) ? q10 : (g == 1) ? q11 : (g == 2) ? q12 : 1.0f;
        const bf16x8 pB0 = frag1(pack2bf(v0, 0.0f));
        const bf16x8 pB1 = frag1(pack2bf(v1, 0.0f));

        // ---- gathers issued early (latency hides under the MFMA pipeline) ----
        float fvA[2][4], fvB[2][4];
        #pragma unroll
        for (int tt = 0; tt < 2; ++tt) {
            const int tb = tt ? tb1 : tb0;
            #pragma unroll
            for (int r = 0; r < 4; ++r) {
                const int2 mp = map2[tb + g*4 + r];
                const int my = mp.x, mx = mp.y;
                int y  = my + dyA, x  = mx + dxA;
                int yc = min(max(y,0),511), xc = min(max(x,0),511);
                float f = fbaseA[yc*512 + xc];
                fvA[tt][r] = (((unsigned)y | (unsigned)x) < 512u) ? f : 0.f;
                int y2 = my + dyB, x2 = mx + dxB;
                int yc2 = min(max(y2,0),511), xc2 = min(max(x2,0),511);
                float f2 = fbaseB[yc2*512 + xc2];
                fvB[tt][r] = (((unsigned)y2 | (unsigned)x2) < 512u) ? f2 : 0.f;
            }
        }

        f32x4 acc00 = {b2A,b2A,b2A,b2A}, acc01 = {b2B,b2B,b2B,b2B};
        f32x4 acc10 = {b2A,b2A,b2A,b2A}, acc11 = {b2B,b2B,b2B,b2B};
        const f32x4 zero = {0.f, 0.f, 0.f, 0.f};

        #pragma unroll
        for (int kc = 0; kc < 8; ++kc) {
            const bf16x8 wA0 = frag1(sW1f[2*kc    ][lane]);
            const bf16x8 wA1 = frag1(sW1f[2*kc + 1][lane]);

            // L1: h[j][px]; lane holds j = 16jt + 4g + reg, px = col
            const f32x4 c00 = __builtin_amdgcn_mfma_f32_16x16x32_bf16(wA0, pB0, zero, 0,0,0);
            const f32x4 c01 = __builtin_amdgcn_mfma_f32_16x16x32_bf16(wA1, pB0, zero, 0,0,0);
            const f32x4 c10 = __builtin_amdgcn_mfma_f32_16x16x32_bf16(wA0, pB1, zero, 0,0,0);
            const f32x4 c11 = __builtin_amdgcn_mfma_f32_16x16x32_bf16(wA1, pB1, zero, 0,0,0);

            // leaky + pack -> L2 A-fragment
            u32x4 a0, a1;
            a0[0] = pack2bf(lk(c00[0]), lk(c00[1]));
            a0[1] = pack2bf(lk(c00[2]), lk(c00[3]));
            a0[2] = pack2bf(lk(c01[0]), lk(c01[1]));
            a0[3] = pack2bf(lk(c01[2]), lk(c01[3]));
            a1[0] = pack2bf(lk(c10[0]), lk(c10[1]));
            a1[1] = pack2bf(lk(c10[2]), lk(c10[3]));
            a1[2] = pack2bf(lk(c11[0]), lk(c11[1]));
            a1[3] = pack2bf(lk(c11[2]), lk(c11[3]));
            const bf16x8 av0 = as_bf16x8(a0);
            const bf16x8 av1 = as_bf16x8(a1);

            const bf16x8 bv0 = sB[kc*2    ][lane];
            const bf16x8 bv1 = sB[kc*2 + 1][lane];
            acc00 = __builtin_amdgcn_mfma_f32_16x16x32_bf16(av0, bv0, acc00, 0,0,0);
            acc01 = __builtin_amdgcn_mfma_f32_16x16x32_bf16(av0, bv1, acc01, 0,0,0);
            acc10 = __builtin_amdgcn_mfma_f32_16x16x32_bf16(av1, bv0, acc10, 0,0,0);
            acc11 = __builtin_amdgcn_mfma_f32_16x16x32_bf16(av1, bv1, acc11, 0,0,0);
        }

        // ---- combine: col=lane&15 (k27), row=g*4+r (pixel); DPP 16-lane sum ----
        #pragma unroll
        for (int tt = 0; tt < 2; ++tt) {
            const int tb = tt ? tb1 : tb0;
            const f32x4 aA = tt ? acc10 : acc00;
            const f32x4 aB = tt ? acc11 : acc01;
            #pragma unroll
            for (int r = 0; r < 4; ++r) {
                float s = aA[r] * fvA[tt][r] + aB[r] * fvB[tt][r];
                DPP_ADD(s, 0xB1);    // quad_perm(1,0,3,2) : xor 1
                DPP_ADD(s, 0x4E);    // quad_perm(2,3,0,1) : xor 2
                DPP_ADD(s, 0x124);   // row_ror:4
                DPP_ADD(s, 0x128);   // row_ror:8
                if (col == r) out[tb + g*4 + r] = s;
            }
        }
    }
}

extern "C" void kernel_launch(void* const* d_in, const int* in_sizes, int n_in,
                              void* d_out, int out_size, void* d_ws, size_t ws_size,
                              hipStream_t stream) {
    const float* pos     = (const float*)d_in[0];
    const int*   mapping = (const int*)d_in[1];
    const float* feats   = (const float*)d_in[2];
    // d_in[3] = depth, unused
    const float* W1      = (const float*)d_in[4];
    const float* b1      = (const float*)d_in[5];
    const float* W2      = (const float*)d_in[6];
    const float* b2      = (const float*)d_in[7];
    float* out = (float*)d_out;

    // P = 1024*1024: 65536 tiles; 2048 blocks x 4 waves x 8 tiles
    mapnet_v10<<<2048, 256, 0, stream>>>(pos, mapping, feats, W1, b1, W2, b2, out);
}